// Round 1
// baseline (353.267 us; speedup 1.0000x reference)
//
#include <hip/hip_runtime.h>

#define B_ 32
#define CD 128
#define O3 384
#define N  4096
#define H_ 4
#define C_ 32

typedef __bf16 bf16x8 __attribute__((ext_vector_type(8)));
typedef float floatx4 __attribute__((ext_vector_type(4)));

#define MFMA16(a, b, c) __builtin_amdgcn_mfma_f32_16x16x32_bf16(a, b, c, 0, 0, 0)

__device__ __forceinline__ float b2f(unsigned int u) {   // low 16 bits
  return __builtin_bit_cast(float, u << 16);
}
__device__ __forceinline__ float b2fh(unsigned int u) {  // high 16 bits
  return __builtin_bit_cast(float, u & 0xffff0000u);
}
__device__ __forceinline__ unsigned short f2b(float f) {
  unsigned int bits = __builtin_bit_cast(unsigned int, f);
  unsigned int r = (bits + 0x7FFFu + ((bits >> 16) & 1u)) >> 16;
  return (unsigned short)r;
}

// ---------------------------------------------------------------------------
// K0a: transpose+convert x [b][c][n] fp32 -> xT [b][n][c] bf16.
// ---------------------------------------------------------------------------
__global__ __launch_bounds__(256) void k0_xt(const float* __restrict__ x,
                                             unsigned short* __restrict__ xT)
{
  __shared__ float xt[32 * 68];
  const int t = threadIdx.x;
  const int n0 = blockIdx.x * 64, c0 = blockIdx.y * 32, b = blockIdx.z;
  const float* xb = x + ((size_t)b * CD + c0) * N + n0;
#pragma unroll
  for (int i = 0; i < 2; i++) {
    int f = i * 256 + t;
    int c = f >> 4, n4 = (f & 15) * 4;
    float4 v = *(const float4*)(xb + (size_t)c * N + n4);
    *(float4*)&xt[c * 68 + n4] = v;
  }
  __syncthreads();
  int n = t >> 2, cb = (t & 3) * 8;
  unsigned short tmp[8];
#pragma unroll
  for (int j = 0; j < 8; j++) tmp[j] = f2b(xt[(cb + j) * 68 + n]);
  *(uint4*)(xT + ((size_t)b * N + n0 + n) * CD + c0 + cb) = *(uint4*)tmp;
}

// ---------------------------------------------------------------------------
// K0b: fused-weight precompute.
//  qkv_wb2[o][dlt*128+c] = bf16(dw_w[o][tap dlt] * qkv_w[o][c])   (384x384)
//  proj_wb = bf16(proj_w)
//  sb[o] = qkv_b[o]*(w0+w1+w2)+dw_b[o]; c0[o]=qkv_b[o]*w0; c2[o]=qkv_b[o]*w2
// (dw taps are column 1 of the 3x3 kernel: indices 1,4,7 since w==1.)
// ---------------------------------------------------------------------------
__global__ void k0_w(const float* __restrict__ qkv_w,
                     const float* __restrict__ proj_w,
                     const float* __restrict__ dw_w,
                     const float* __restrict__ dw_b,
                     const float* __restrict__ qkv_b,
                     unsigned short* __restrict__ qkv_wb2,
                     unsigned short* __restrict__ proj_wb,
                     float* __restrict__ sb,
                     float* __restrict__ c0,
                     float* __restrict__ c2)
{
  int e = blockIdx.x * 256 + threadIdx.x;
  if (e < 36864) {                       // 384*384/4
    int base = e * 4;
    int o = base / 384;
    int k = base - o * 384;
    int dlt = k >> 7, c = k & 127;
    float w = dw_w[o * 9 + 1 + 3 * dlt];
    float4 q = *(const float4*)(qkv_w + o * 128 + c);
    unsigned short tmp[4] = {f2b(w * q.x), f2b(w * q.y), f2b(w * q.z),
                             f2b(w * q.w)};
    *(uint2*)(qkv_wb2 + base) = *(uint2*)tmp;
  } else if (e < 40960) {                // proj: 128*128/4
    int base = (e - 36864) * 4;
    float4 v = *(const float4*)(proj_w + base);
    unsigned short tmp[4] = {f2b(v.x), f2b(v.y), f2b(v.z), f2b(v.w)};
    *(uint2*)(proj_wb + base) = *(uint2*)tmp;
  } else if (e < 41344) {                // 384 fused biases
    int o = e - 40960;
    float w0 = dw_w[o * 9 + 1], w1 = dw_w[o * 9 + 4], w2 = dw_w[o * 9 + 7];
    float qb = qkv_b[o], db = dw_b[o];
    sb[o] = qb * (w0 + w1 + w2) + db;
    c0[o] = qb * w0;
    c2[o] = qb * w2;
  }
}

// ---------------------------------------------------------------------------
// K1: conv-folded MFMA GEMM. K=384 (3 dw taps x 128 c); the dlt-th K-block
// reads the SAME 32KB staged x-tile with rows shifted by dlt, so the 3-tap
// depthwise conv is free. No epilogue barriers, no pres round-trip.
// Staged rows r <-> y = ybase-1+r (zeroed outside [0,N)) -> conv zero-pad
// falls out of staging. Bias is analytic: sb[o] (+edge corrections c0/c2).
// LDS 128x128 bf16 = 32768 B, 16B-chunk XOR swizzle (chunk ^= row&15):
// conflict-free staging writes AND row-shifted ds_read_b128.
// q,k blocks (otile<2): D[o][y] -> qkvd[b][o][y].
// v blocks  (otile==2): operands swapped -> D[y][o] -> vT[b][y][c].
// grid (33, 3, 32), 256 thr, 126 output rows/block.
// ---------------------------------------------------------------------------
__global__ __launch_bounds__(256, 4) void k1_qkv_dw(
    const unsigned short* __restrict__ xT,
    const unsigned short* __restrict__ qkv_wb2,
    const float* __restrict__ sb, const float* __restrict__ c0,
    const float* __restrict__ c2, unsigned short* __restrict__ qkvd,
    unsigned short* __restrict__ vT)
{
  __shared__ unsigned short Bs[128 * 128];   // 32768 B exactly
  const int t = threadIdx.x;
  const int ytile = blockIdx.x, otile = blockIdx.y, b = blockIdx.z;
  const int obase = otile * 128;
  const int ybase = ytile * 126;
  const int wv = t >> 6, l = t & 63, quad = l >> 4, lm = l & 15;

  // stage 128 rows: row r <-> y = ybase-1+r, zero outside [0,N)
#pragma unroll
  for (int i = 0; i < 8; i++) {
    int f = i * 256 + t;
    int row = f >> 4, ch = f & 15;
    int yg = ybase - 1 + row;
    uint4 v = make_uint4(0u, 0u, 0u, 0u);
    if (yg >= 0 && yg < N)
      v = *(const uint4*)(xT + ((size_t)b * N + yg) * CD + ch * 8);
    *(uint4*)&Bs[row * 128 + ((ch ^ (row & 15)) << 3)] = v;
  }
  __syncthreads();

  const unsigned short* wbase =
      qkv_wb2 + (size_t)(obase + wv * 32 + lm) * 384 + quad * 8;
  const bool edge = (ybase == 0) || (ybase + 126 >= N);

  if (otile < 2) {
    // ---------------- q,k: D[row=o][col=y] ----------------
    floatx4 acc[2][8];
#pragma unroll
    for (int mt = 0; mt < 2; mt++)
#pragma unroll
      for (int nt = 0; nt < 8; nt++) acc[mt][nt] = (floatx4){0.f, 0.f, 0.f, 0.f};

#pragma unroll
    for (int ks = 0; ks < 12; ks++) {
      bf16x8 a0 = *(const bf16x8*)(wbase + ks * 32);
      bf16x8 a1 = *(const bf16x8*)(wbase + 16 * 384 + ks * 32);
      const int dlt = ks >> 2, cpart = ks & 3;
      const int swz = (((cpart << 2) + quad) ^ ((lm + dlt) & 15)) << 3;
#pragma unroll
      for (int nt = 0; nt < 8; nt++) {
        int rr = nt * 16 + lm + dlt;
        if (nt == 7) rr = (rr > 127) ? 127 : rr;   // OOB lanes' cols are masked
        bf16x8 bb = *(const bf16x8*)&Bs[rr * 128 + swz];
        acc[0][nt] = MFMA16(a0, bb, acc[0][nt]);
        acc[1][nt] = MFMA16(a1, bb, acc[1][nt]);
      }
    }

#pragma unroll
    for (int mt = 0; mt < 2; mt++)
#pragma unroll
      for (int r = 0; r < 4; r++) {
        const int o = obase + wv * 32 + mt * 16 + quad * 4 + r;
        const float bias = sb[o];
        float c0v = 0.f, c2v = 0.f;
        if (edge) { c0v = c0[o]; c2v = c2[o]; }
        const size_t orow = ((size_t)b * 256 + o) * N;
#pragma unroll
        for (int nt = 0; nt < 8; nt++) {
          int iy = nt * 16 + lm;
          int y = ybase + iy;
          float val = acc[mt][nt][r] + bias;
          if (y == 0) val -= c0v;
          if (y == N - 1) val -= c2v;
          if (iy < 126 && y < N) qkvd[orow + y] = f2b(val);
        }
      }
  } else {
    // ---------------- v: swapped operands, D[row=y][col=o] ----------------
    floatx4 acc[8][2];
#pragma unroll
    for (int nt = 0; nt < 8; nt++)
#pragma unroll
      for (int mt = 0; mt < 2; mt++) acc[nt][mt] = (floatx4){0.f, 0.f, 0.f, 0.f};

#pragma unroll
    for (int ks = 0; ks < 12; ks++) {
      bf16x8 a0 = *(const bf16x8*)(wbase + ks * 32);
      bf16x8 a1 = *(const bf16x8*)(wbase + 16 * 384 + ks * 32);
      const int dlt = ks >> 2, cpart = ks & 3;
      const int swz = (((cpart << 2) + quad) ^ ((lm + dlt) & 15)) << 3;
#pragma unroll
      for (int nt = 0; nt < 8; nt++) {
        int rr = nt * 16 + lm + dlt;
        if (nt == 7) rr = (rr > 127) ? 127 : rr;   // OOB lanes' rows are masked
        bf16x8 bb = *(const bf16x8*)&Bs[rr * 128 + swz];
        acc[nt][0] = MFMA16(bb, a0, acc[nt][0]);
        acc[nt][1] = MFMA16(bb, a1, acc[nt][1]);
      }
    }

#pragma unroll
    for (int mt = 0; mt < 2; mt++) {
      const int ol = wv * 32 + mt * 16 + lm;          // v channel 0..127
      const float bias = sb[256 + ol];
      float c0v = 0.f, c2v = 0.f;
      if (edge) { c0v = c0[256 + ol]; c2v = c2[256 + ol]; }
#pragma unroll
      for (int nt = 0; nt < 8; nt++)
#pragma unroll
        for (int r = 0; r < 4; r++) {
          int iy = nt * 16 + quad * 4 + r;
          int y = ybase + iy;
          float val = acc[nt][mt][r] + bias;
          if (y == 0) val -= c0v;
          if (y == N - 1) val -= c2v;
          if (iy < 126 && y < N)
            vT[((size_t)b * N + y) * CD + ol] = f2b(val);
        }
    }
  }
}

// ---------------------------------------------------------------------------
// K3: MFMA Gram, fragments loaded straight from global (K-major layout),
// no staging barriers. 32x32 QK^T partial over 1024 n + Q/K norms via
// self-MFMA diagonals. part[b][h][ns][2048]. grid (4, H, B), 256 thr.
// ---------------------------------------------------------------------------
__global__ __launch_bounds__(256, 4) void k3_gram(
    const unsigned short* __restrict__ qkvd, float* __restrict__ part)
{
  __shared__ float red[4 * 8 * 272];   // [wv][tile][row*17+col]
  const int ns = blockIdx.x, h = blockIdx.y, b = blockIdx.z;
  const int t = threadIdx.x;
  const int wv = t >> 6, l = t & 63, quad = l >> 4, lm = l & 15;
  const unsigned short* qb = qkvd + ((size_t)b * 256 + h * C_) * N;
  const unsigned short* kb = qkvd + ((size_t)b * 256 + 128 + h * C_) * N;

  floatx4 acc[8];
#pragma unroll
  for (int i = 0; i < 8; i++) acc[i] = (floatx4){0.f, 0.f, 0.f, 0.f};

  const int nbase = ns * 1024 + wv * 32 + quad * 8;
#pragma unroll
  for (int ch = 0; ch < 8; ch++) {
    int nc = nbase + ch * 128;
    bf16x8 a0 = *(const bf16x8*)(qb + (size_t)lm * N + nc);
    bf16x8 a1 = *(const bf16x8*)(qb + (size_t)(16 + lm) * N + nc);
    bf16x8 b0 = *(const bf16x8*)(kb + (size_t)lm * N + nc);
    bf16x8 b1 = *(const bf16x8*)(kb + (size_t)(16 + lm) * N + nc);
    acc[0] = MFMA16(a0, b0, acc[0]);
    acc[1] = MFMA16(a0, b1, acc[1]);
    acc[2] = MFMA16(a1, b0, acc[2]);
    acc[3] = MFMA16(a1, b1, acc[3]);
    acc[4] = MFMA16(a0, a0, acc[4]);
    acc[5] = MFMA16(a1, a1, acc[5]);
    acc[6] = MFMA16(b0, b0, acc[6]);
    acc[7] = MFMA16(b1, b1, acc[7]);
  }

#pragma unroll
  for (int tl = 0; tl < 8; tl++)
#pragma unroll
    for (int r = 0; r < 4; r++)
      red[wv * 2176 + tl * 272 + (quad * 4 + r) * 17 + lm] = acc[tl][r];
  __syncthreads();

  float* pb = part + ((size_t)(b * H_ + h) * 4 + ns) * 2048;
  for (int e = t; e < 2048; e += 256) {
    int tl = e >> 8, rc = e & 255, row = rc >> 4, col = rc & 15;
    int a = tl * 272 + row * 17 + col;
    float s = red[a] + red[2176 + a] + red[2 * 2176 + a] + red[3 * 2176 + a];
    if (tl < 4) {
      int mt = tl >> 1, nt = tl & 1;
      pb[(mt * 16 + row) * 32 + nt * 16 + col] = s;
    } else if (row == col) {
      if (tl < 6) pb[1024 + (tl - 4) * 16 + row] = s;
      else        pb[1056 + (tl - 6) * 16 + row] = s;
    }
  }
}

// ---------------------------------------------------------------------------
// K45: sum partials, normalize+temperature, exact stable top-k ranks, fold
// 4 masked softmaxes -> AwtT bf16; M = proj_w @ blockdiag(A) via MFMA.
// grid (B), 256 thr.
// ---------------------------------------------------------------------------
__global__ __launch_bounds__(256) void k45(
    const float* __restrict__ part, const unsigned short* __restrict__ proj_wb,
    const float* __restrict__ temperature, const float* __restrict__ attn_w,
    unsigned short* __restrict__ Mb)
{
  __shared__ float La[H_][C_][33];
  __shared__ float sq2[256];
  __shared__ float rn[256];
  __shared__ float exL[H_][C_][33];
  __shared__ unsigned char rkL[H_][C_][C_];
  __shared__ unsigned short AwtT[H_][C_][40];
  const int b = blockIdx.x, t = threadIdx.x;

  const float* pbb = part + (size_t)b * 32768;
  for (int e = t; e < 4 * 2048; e += 256) {
    int h = e >> 11, idx = e & 2047;
    if (idx < 1088) {
      const float* p = pbb + h * 8192 + idx;
      float s = p[0] + p[2048] + p[2 * 2048] + p[3 * 2048];
      if (idx < 1024) La[h][idx >> 5][idx & 31] = s;
      else if (idx < 1056) sq2[h * 32 + (idx - 1024)] = s;
      else sq2[128 + h * 32 + (idx - 1056)] = s;
    }
  }
  __syncthreads();
  rn[t] = 1.f / fmaxf(sqrtf(sq2[t]), 1e-12f);
  __syncthreads();
  for (int e = t; e < 4096; e += 256) {
    int h = e >> 10, i = (e >> 5) & 31, j = e & 31;
    La[h][i][j] *= rn[h * 32 + i] * rn[128 + h * 32 + j] * temperature[h];
  }
  __syncthreads();

  if (t < 128) {
    int h = t >> 5, i = t & 31;
    float m = -1e30f;
    for (int j = 0; j < 32; j++) m = fmaxf(m, La[h][i][j]);
    float S0 = 0.f, S1 = 0.f, S2 = 0.f, S3 = 0.f;
    for (int j = 0; j < 32; j++) {
      float vj = La[h][i][j];
      int r = 0;
      for (int j2 = 0; j2 < 32; j2++) {
        float v2 = La[h][i][j2];
        r += (v2 > vj) || (v2 == vj && j2 < j);
      }
      float e = __expf(vj - m);
      exL[h][i][j] = e;
      rkL[h][i][j] = (unsigned char)r;
      if (r < 16) S0 += e;
      if (r < 21) S1 += e;
      if (r < 24) S2 += e;
      if (r < 25) S3 += e;
    }
    float w0 = attn_w[0] / S0, w1 = attn_w[1] / S1;
    float w2 = attn_w[2] / S2, w3 = attn_w[3] / S3;
    for (int j = 0; j < 32; j++) {
      int r = rkL[h][i][j];
      float cmb = (r < 16 ? w0 : 0.f) + (r < 21 ? w1 : 0.f) +
                  (r < 24 ? w2 : 0.f) + (r < 25 ? w3 : 0.f);
      AwtT[h][j][i] = f2b(exL[h][i][j] * cmb);
    }
  }
  __syncthreads();

  {
    const int wv = t >> 6, l = t & 63, quad = l >> 4, lm = l & 15;
    const int h = wv;
    bf16x8 bfr[2];
#pragma unroll
    for (int jt = 0; jt < 2; jt++)
      bfr[jt] = *(const bf16x8*)&AwtT[h][jt * 16 + lm][quad * 8];
#pragma unroll
    for (int mt = 0; mt < 8; mt++) {
      bf16x8 a = *(const bf16x8*)(proj_wb +
                    (size_t)(mt * 16 + lm) * CD + h * C_ + quad * 8);
#pragma unroll
      for (int jt = 0; jt < 2; jt++) {
        floatx4 acc = (floatx4){0.f, 0.f, 0.f, 0.f};
        acc = MFMA16(a, bfr[jt], acc);
#pragma unroll
        for (int r = 0; r < 4; r++) {
          int row = quad * 4 + r;
          Mb[(size_t)b * 16384 + (mt * 16 + row) * CD + h * C_ + jt * 16 + lm] =
              f2b(acc[r]);
        }
      }
    }
  }
}

// ---------------------------------------------------------------------------
// K6: out[b] = Mb @ V^T + proj_b. A (Mb) per-ks from global (L2-hot);
// LDS = Bs only -> 4 blocks/CU. grid (32, 32), 256 thr.
// ---------------------------------------------------------------------------
__global__ __launch_bounds__(256, 4) void k6_out(
    const unsigned short* __restrict__ vT, const unsigned short* __restrict__ Mb,
    const float* __restrict__ proj_b, float* __restrict__ out)
{
  __shared__ unsigned short Bs[128 * 136];
  const int t = threadIdx.x;
  const int y0 = blockIdx.x * 128, b = blockIdx.y;
  const int wv = t >> 6, l = t & 63, quad = l >> 4, lm = l & 15;

#pragma unroll
  for (int i = 0; i < 8; i++) {
    int f = i * 256 + t;
    int row = f >> 4, c8 = (f & 15) * 8;
    *(uint4*)&Bs[row * 136 + c8] =
        *(const uint4*)(vT + ((size_t)b * N + y0 + row) * CD + c8);
  }
  __syncthreads();

  floatx4 acc[2][8];
#pragma unroll
  for (int mt = 0; mt < 2; mt++)
#pragma unroll
    for (int nt = 0; nt < 8; nt++) acc[mt][nt] = (floatx4){0.f, 0.f, 0.f, 0.f};

  const unsigned short* mbase =
      Mb + (size_t)b * 16384 + (size_t)(wv * 32 + lm) * CD + quad * 8;
#pragma unroll
  for (int ks = 0; ks < 4; ks++) {
    bf16x8 a0 = *(const bf16x8*)(mbase + ks * 32);
    bf16x8 a1 = *(const bf16x8*)(mbase + 16 * CD + ks * 32);
#pragma unroll
    for (int nt = 0; nt < 8; nt++) {
      bf16x8 bb = *(const bf16x8*)&Bs[(nt * 16 + lm) * 136 + ks * 32 + quad * 8];
      acc[0][nt] = MFMA16(a0, bb, acc[0][nt]);
      acc[1][nt] = MFMA16(a1, bb, acc[1][nt]);
    }
  }

#pragma unroll
  for (int mt = 0; mt < 2; mt++)
#pragma unroll
    for (int r = 0; r < 4; r++) {
      int o = wv * 32 + mt * 16 + quad * 4 + r;
      float pb = proj_b[o];
#pragma unroll
      for (int nt = 0; nt < 8; nt++) {
        int y = y0 + nt * 16 + lm;
        out[((size_t)b * CD + o) * N + y] = acc[mt][nt][r] + pb;
      }
    }
}

extern "C" void kernel_launch(void* const* d_in, const int* in_sizes, int n_in,
                              void* d_out, int out_size, void* d_ws, size_t ws_size,
                              hipStream_t stream)
{
  (void)in_sizes; (void)n_in; (void)out_size; (void)ws_size;
  const float* x           = (const float*)d_in[0];
  const float* qkv_w       = (const float*)d_in[1];
  const float* qkv_b       = (const float*)d_in[2];
  const float* dw_w        = (const float*)d_in[3];
  const float* dw_b        = (const float*)d_in[4];
  const float* proj_w      = (const float*)d_in[5];
  const float* proj_b      = (const float*)d_in[6];
  const float* temperature = (const float*)d_in[7];
  const float* attn_w      = (const float*)d_in[8];
  float* out = (float*)d_out;

  unsigned short* xT      = (unsigned short*)d_ws;   // 16,777,216 sh
  unsigned short* proj_wb = xT + (size_t)16777216;   //     16,384 sh
  unsigned short* qkvd    = proj_wb + 16384;         // 33,554,432 (q,k)
  unsigned short* vT      = qkvd + (size_t)33554432; // 16,777,216
  unsigned short* Mb      = vT + (size_t)16777216;   //    524,288
  float* part = (float*)(Mb + 524288);               //  1,048,576 f
  // Aliases (lifetimes disjoint within one launch):
  //  qkv_wb2 (147,456 sh) lives in Mb's slot: written k0_w, read k1,
  //    dead before k45 writes Mb.
  //  sb/c0/c2 (3*384 f) live at the head of part: written k0_w, read k1,
  //    dead before k3 writes part.
  unsigned short* qkv_wb2 = Mb;
  float* sb = part;
  float* c0 = part + 384;
  float* c2 = part + 768;

  k0_xt    <<<dim3(64, 4, 32),  256, 0, stream>>>(x, xT);
  k0_w     <<<dim3(162),        256, 0, stream>>>(qkv_w, proj_w, dw_w, dw_b,
                                                  qkv_b, qkv_wb2, proj_wb,
                                                  sb, c0, c2);
  k1_qkv_dw<<<dim3(33, 3, 32),  256, 0, stream>>>(xT, qkv_wb2, sb, c0, c2,
                                                  qkvd, vT);
  k3_gram  <<<dim3(4, H_, B_),  256, 0, stream>>>(qkvd, part);
  k45      <<<dim3(B_),         256, 0, stream>>>(part, proj_wb, temperature,
                                                  attn_w, Mb);
  k6_out   <<<dim3(32, B_),     256, 0, stream>>>(vT, Mb, proj_b, out);
}

// Round 2
// 296.231 us; speedup vs baseline: 1.1925x; 1.1925x over previous
//
#include <hip/hip_runtime.h>

#define B_ 32
#define CD 128
#define O3 384
#define N  4096
#define H_ 4
#define C_ 32

typedef __bf16 bf16x8 __attribute__((ext_vector_type(8)));
typedef float floatx4 __attribute__((ext_vector_type(4)));

#define MFMA16(a, b, c) __builtin_amdgcn_mfma_f32_16x16x32_bf16(a, b, c, 0, 0, 0)

__device__ __forceinline__ float b2f(unsigned int u) {   // low 16 bits
  return __builtin_bit_cast(float, u << 16);
}
__device__ __forceinline__ float b2fh(unsigned int u) {  // high 16 bits
  return __builtin_bit_cast(float, u & 0xffff0000u);
}
__device__ __forceinline__ unsigned short f2b(float f) {
  unsigned int bits = __builtin_bit_cast(unsigned int, f);
  unsigned int r = (bits + 0x7FFFu + ((bits >> 16) & 1u)) >> 16;
  return (unsigned short)r;
}

// pres index maps (swizzled, 128-short rows, 32KB total):
//  q,k layout pres[o][j]: short idx = o*128 + (j ^ ((o&12)<<1))
//    - pairs (j even) preserved -> uint reads stay valid
//    - write: 4 quads differ in (o&12) -> disjoint bank windows
//  v layout  pres[i][o]: short idx = i*128 + (o ^ ((i&15)<<3))
//    - write: lanes vary i (lm) -> banks (o/2 ^ 4*lm) spread
//    - read: i uniform, lanes vary o -> 32 distinct dwords/wave
#define QIDX(o, j) ((o) * 128 + ((j) ^ (((o) & 12) << 1)))
#define PIDX(i, o) ((i) * 128 + ((o) ^ (((i) & 15) << 3)))

// ---------------------------------------------------------------------------
// K0a: transpose+convert x [b][c][n] fp32 -> xT [b][n][c] bf16.
// stride 69 (was 68): read phase banks (5c+n), c-stride-8 groups now offset
// by 8 banks -> 2-way (free) instead of 4-way.
// ---------------------------------------------------------------------------
__global__ __launch_bounds__(256) void k0_xt(const float* __restrict__ x,
                                             unsigned short* __restrict__ xT)
{
  __shared__ float xt[32 * 69];
  const int t = threadIdx.x;
  const int n0 = blockIdx.x * 64, c0 = blockIdx.y * 32, b = blockIdx.z;
  const float* xb = x + ((size_t)b * CD + c0) * N + n0;
#pragma unroll
  for (int i = 0; i < 2; i++) {
    int f = i * 256 + t;
    int c = f >> 4, n4 = (f & 15) * 4;
    float4 v = *(const float4*)(xb + (size_t)c * N + n4);
    *(float4*)&xt[c * 69 + n4] = v;
  }
  __syncthreads();
  int n = t >> 2, cb = (t & 3) * 8;
  unsigned short tmp[8];
#pragma unroll
  for (int j = 0; j < 8; j++) tmp[j] = f2b(xt[(cb + j) * 69 + n]);
  *(uint4*)(xT + ((size_t)b * N + n0 + n) * CD + c0 + cb) = *(uint4*)tmp;
}

// K0b: qkv_w and proj_w fp32 -> bf16.
__global__ void k0_w(const float* __restrict__ qkv_w,
                     const float* __restrict__ proj_w,
                     unsigned short* __restrict__ qkv_wb,
                     unsigned short* __restrict__ proj_wb)
{
  int e = (blockIdx.x * 256 + threadIdx.x) * 4;
  const float* src; unsigned short* dst; int off;
  if (e < 49152) { src = qkv_w; dst = qkv_wb; off = e; }
  else           { src = proj_w; dst = proj_wb; off = e - 49152; }
  float4 v = *(const float4*)(src + off);
  unsigned short tmp[4] = {f2b(v.x), f2b(v.y), f2b(v.z), f2b(v.w)};
  *(uint2*)(dst + off) = *(uint2*)tmp;
}

// ---------------------------------------------------------------------------
// K1: MFMA GEMM (128o x 124y outputs, 128 staged rows incl. 2+2 halo, K=128)
// + bias + 3-tap depthwise + bias. A-operand (weights) from global per-ks
// (L2-hot, no LDS); LDS = 32,768 B exactly (XOR-swizzled Bs / pres alias)
// -> 5 blocks/CU (was 4 at 34,816 B).
// q,k -> qkvd[b][o2][n]; v -> vT[b][n][c]. grid (34, 3, 32), 256 thr.
// ---------------------------------------------------------------------------
__global__ __launch_bounds__(256, 5) void k1_qkv_dw(
    const unsigned short* __restrict__ xT, const unsigned short* __restrict__ qkv_wb,
    const float* __restrict__ qkv_b, const float* __restrict__ dw_w,
    const float* __restrict__ dw_b, unsigned short* __restrict__ qkvd,
    unsigned short* __restrict__ vT)
{
  __shared__ __align__(16) char smem[32768];
  unsigned short* Bs   = (unsigned short*)smem;   // [128][128] swizzled
  unsigned short* pres = (unsigned short*)smem;   // bf16 pre-dw tile (alias)

  const int t = threadIdx.x;
  const int ytile = blockIdx.x, otile = blockIdx.y, b = blockIdx.z;
  const int obase = otile * 128;
  const int ybase = ytile * 124;                  // first output y (even)
  const int wv = t >> 6, l = t & 63, quad = l >> 4, lm = l & 15;

  // stage B: rows i=0..127 <-> y = ybase-2+i (zero outside [0,N))
  // 16B-chunk XOR swizzle: chunk ch stored at (ch ^ (row&15))
#pragma unroll
  for (int i = 0; i < 8; i++) {
    int f = i * 256 + t;
    int row = f >> 4, ch = f & 15;
    int yg = ybase - 2 + row;
    uint4 v = make_uint4(0u, 0u, 0u, 0u);
    if (yg >= 0 && yg < N)
      v = *(const uint4*)(xT + ((size_t)b * N + yg) * CD + ch * 8);
    *(uint4*)&Bs[row * 128 + ((ch ^ (row & 15)) << 3)] = v;
  }
  __syncthreads();

  floatx4 acc[2][8];
#pragma unroll
  for (int mt = 0; mt < 2; mt++)
#pragma unroll
    for (int nt = 0; nt < 8; nt++) acc[mt][nt] = (floatx4){0.f, 0.f, 0.f, 0.f};

  const unsigned short* wbase =
      qkv_wb + (size_t)(obase + wv * 32 + lm) * CD + quad * 8;
#pragma unroll
  for (int ks = 0; ks < 4; ks++) {
    bf16x8 a0 = *(const bf16x8*)(wbase + ks * 32);
    bf16x8 a1 = *(const bf16x8*)(wbase + 16 * CD + ks * 32);
#pragma unroll
    for (int nt = 0; nt < 8; nt++) {
      bf16x8 bb = *(const bf16x8*)
          &Bs[(nt * 16 + lm) * 128 + (((ks * 4 + quad) ^ lm) << 3)];
      acc[0][nt] = MFMA16(a0, bb, acc[0][nt]);
      acc[1][nt] = MFMA16(a1, bb, acc[1][nt]);
    }
  }

  if (otile < 2) {
    // ---- q,k: pres[o][j] (j = local row - 1, j in [0,126]), swizzled
    __syncthreads();
#pragma unroll
    for (int mt = 0; mt < 2; mt++)
#pragma unroll
      for (int r = 0; r < 4; r++) {
        int o = wv * 32 + mt * 16 + quad * 4 + r;
        float bias = qkv_b[obase + o];
#pragma unroll
        for (int nt = 0; nt < 8; nt++) {
          int i = nt * 16 + lm;
          if (i >= 1) {
            int yg = ybase - 2 + i;
            pres[QIDX(o, i - 1)] =
                f2b((yg >= 0 && yg < N) ? (acc[mt][nt][r] + bias) : 0.f);
          }
        }
      }
    __syncthreads();
    // y-pair sweep: wave-uniform o, lanes cover 62 aligned pairs
    const int p = t & 63, og = t >> 6;
    const bool ok = (p < 62) && (ybase + 2 * p < N);
    const unsigned int* presu = (const unsigned int*)pres;  // pairs of bf16
    for (int r2 = 0; r2 < 32; r2++) {
      int oo = __builtin_amdgcn_readfirstlane(obase + og * 32 + r2);
      float w0 = dw_w[oo * 9 + 1], w1 = dw_w[oo * 9 + 4],
            w2 = dw_w[oo * 9 + 7], db = dw_b[oo];
      int o = oo - obase;
      unsigned int u0 = presu[o * 64 + (p ^ (o & 12))];
      unsigned int u1 = presu[o * 64 + ((p + 1) ^ (o & 12))];
      float v0 = b2f(u0), v1 = b2fh(u0), v2 = b2f(u1), v3 = b2fh(u1);
      float out0 = w0 * v0 + w1 * v1 + w2 * v2 + db;
      float out1 = w0 * v1 + w1 * v2 + w2 * v3 + db;
      unsigned int pk = (unsigned int)f2b(out0) |
                        ((unsigned int)f2b(out1) << 16);
      if (ok)
        *(unsigned int*)(qkvd + ((size_t)b * 256 + oo) * N + ybase + 2 * p) = pk;
    }
  } else {
    // ---- v: pres[i][o] swizzled; per-lane o, sliding window over y
    const int o = t & 127, half = t >> 7;
    const int oo = obase + o;
    const float w0 = dw_w[oo * 9 + 1], w1 = dw_w[oo * 9 + 4],
                w2 = dw_w[oo * 9 + 7], db = dw_b[oo];
    __syncthreads();
#pragma unroll
    for (int mt = 0; mt < 2; mt++)
#pragma unroll
      for (int r = 0; r < 4; r++) {
        int o2 = wv * 32 + mt * 16 + quad * 4 + r;
        float bias = qkv_b[obase + o2];
#pragma unroll
        for (int nt = 0; nt < 8; nt++) {
          int i = nt * 16 + lm;
          int yg = ybase - 2 + i;
          pres[PIDX(i, o2)] =
              f2b((yg >= 0 && yg < N) ? (acc[mt][nt][r] + bias) : 0.f);
        }
      }
    __syncthreads();
    int i0 = 2 + half * 62;                     // halves: i 2..63, 64..125
    float pm = b2f((unsigned int)pres[PIDX(i0 - 1, o)]);
    float pc = b2f((unsigned int)pres[PIDX(i0, o)]);
    for (int i = i0; i < i0 + 62; i++) {
      float pp = b2f((unsigned int)pres[PIDX(i + 1, o)]);
      int yo = ybase - 2 + i;
      if (yo < N) {
        float v = w0 * pm + w1 * pc + w2 * pp + db;
        vT[((size_t)b * N + yo) * CD + o] = f2b(v);
      }
      pm = pc; pc = pp;
    }
  }
}

// ---------------------------------------------------------------------------
// K3: MFMA Gram, fragments loaded straight from global (K-major layout),
// no staging barriers. 32x32 QK^T partial over 1024 n + Q/K norms via
// self-MFMA diagonals. part[b][h][ns][2048]. grid (4, H, B), 256 thr.
// ---------------------------------------------------------------------------
__global__ __launch_bounds__(256, 4) void k3_gram(
    const unsigned short* __restrict__ qkvd, float* __restrict__ part)
{
  __shared__ float red[4 * 8 * 272];   // [wv][tile][row*17+col]
  const int ns = blockIdx.x, h = blockIdx.y, b = blockIdx.z;
  const int t = threadIdx.x;
  const int wv = t >> 6, l = t & 63, quad = l >> 4, lm = l & 15;
  const unsigned short* qb = qkvd + ((size_t)b * 256 + h * C_) * N;
  const unsigned short* kb = qkvd + ((size_t)b * 256 + 128 + h * C_) * N;

  floatx4 acc[8];
#pragma unroll
  for (int i = 0; i < 8; i++) acc[i] = (floatx4){0.f, 0.f, 0.f, 0.f};

  const int nbase = ns * 1024 + wv * 32 + quad * 8;
#pragma unroll
  for (int ch = 0; ch < 8; ch++) {
    int nc = nbase + ch * 128;
    bf16x8 a0 = *(const bf16x8*)(qb + (size_t)lm * N + nc);
    bf16x8 a1 = *(const bf16x8*)(qb + (size_t)(16 + lm) * N + nc);
    bf16x8 b0 = *(const bf16x8*)(kb + (size_t)lm * N + nc);
    bf16x8 b1 = *(const bf16x8*)(kb + (size_t)(16 + lm) * N + nc);
    acc[0] = MFMA16(a0, b0, acc[0]);
    acc[1] = MFMA16(a0, b1, acc[1]);
    acc[2] = MFMA16(a1, b0, acc[2]);
    acc[3] = MFMA16(a1, b1, acc[3]);
    acc[4] = MFMA16(a0, a0, acc[4]);
    acc[5] = MFMA16(a1, a1, acc[5]);
    acc[6] = MFMA16(b0, b0, acc[6]);
    acc[7] = MFMA16(b1, b1, acc[7]);
  }

#pragma unroll
  for (int tl = 0; tl < 8; tl++)
#pragma unroll
    for (int r = 0; r < 4; r++)
      red[wv * 2176 + tl * 272 + (quad * 4 + r) * 17 + lm] = acc[tl][r];
  __syncthreads();

  float* pb = part + ((size_t)(b * H_ + h) * 4 + ns) * 2048;
  for (int e = t; e < 2048; e += 256) {
    int tl = e >> 8, rc = e & 255, row = rc >> 4, col = rc & 15;
    int a = tl * 272 + row * 17 + col;
    float s = red[a] + red[2176 + a] + red[2 * 2176 + a] + red[3 * 2176 + a];
    if (tl < 4) {
      int mt = tl >> 1, nt = tl & 1;
      pb[(mt * 16 + row) * 32 + nt * 16 + col] = s;
    } else if (row == col) {
      if (tl < 6) pb[1024 + (tl - 4) * 16 + row] = s;
      else        pb[1056 + (tl - 6) * 16 + row] = s;
    }
  }
}

// ---------------------------------------------------------------------------
// K45: sum partials, normalize+temperature, exact stable top-k ranks, fold
// 4 masked softmaxes -> AwtT bf16; M = proj_w @ blockdiag(A) via MFMA.
// grid (B), 256 thr.
// ---------------------------------------------------------------------------
__global__ __launch_bounds__(256) void k45(
    const float* __restrict__ part, const unsigned short* __restrict__ proj_wb,
    const float* __restrict__ temperature, const float* __restrict__ attn_w,
    unsigned short* __restrict__ Mb)
{
  __shared__ float La[H_][C_][33];
  __shared__ float sq2[256];
  __shared__ float rn[256];
  __shared__ float exL[H_][C_][33];
  __shared__ unsigned char rkL[H_][C_][C_];
  __shared__ unsigned short AwtT[H_][C_][40];
  const int b = blockIdx.x, t = threadIdx.x;

  const float* pbb = part + (size_t)b * 32768;
  for (int e = t; e < 4 * 2048; e += 256) {
    int h = e >> 11, idx = e & 2047;
    if (idx < 1088) {
      const float* p = pbb + h * 8192 + idx;
      float s = p[0] + p[2048] + p[2 * 2048] + p[3 * 2048];
      if (idx < 1024) La[h][idx >> 5][idx & 31] = s;
      else if (idx < 1056) sq2[h * 32 + (idx - 1024)] = s;
      else sq2[128 + h * 32 + (idx - 1056)] = s;
    }
  }
  __syncthreads();
  rn[t] = 1.f / fmaxf(sqrtf(sq2[t]), 1e-12f);
  __syncthreads();
  for (int e = t; e < 4096; e += 256) {
    int h = e >> 10, i = (e >> 5) & 31, j = e & 31;
    La[h][i][j] *= rn[h * 32 + i] * rn[128 + h * 32 + j] * temperature[h];
  }
  __syncthreads();

  if (t < 128) {
    int h = t >> 5, i = t & 31;
    float m = -1e30f;
    for (int j = 0; j < 32; j++) m = fmaxf(m, La[h][i][j]);
    float S0 = 0.f, S1 = 0.f, S2 = 0.f, S3 = 0.f;
    for (int j = 0; j < 32; j++) {
      float vj = La[h][i][j];
      int r = 0;
      for (int j2 = 0; j2 < 32; j2++) {
        float v2 = La[h][i][j2];
        r += (v2 > vj) || (v2 == vj && j2 < j);
      }
      float e = __expf(vj - m);
      exL[h][i][j] = e;
      rkL[h][i][j] = (unsigned char)r;
      if (r < 16) S0 += e;
      if (r < 21) S1 += e;
      if (r < 24) S2 += e;
      if (r < 25) S3 += e;
    }
    float w0 = attn_w[0] / S0, w1 = attn_w[1] / S1;
    float w2 = attn_w[2] / S2, w3 = attn_w[3] / S3;
    for (int j = 0; j < 32; j++) {
      int r = rkL[h][i][j];
      float cmb = (r < 16 ? w0 : 0.f) + (r < 21 ? w1 : 0.f) +
                  (r < 24 ? w2 : 0.f) + (r < 25 ? w3 : 0.f);
      AwtT[h][j][i] = f2b(exL[h][i][j] * cmb);
    }
  }
  __syncthreads();

  {
    const int wv = t >> 6, l = t & 63, quad = l >> 4, lm = l & 15;
    const int h = wv;
    bf16x8 bfr[2];
#pragma unroll
    for (int jt = 0; jt < 2; jt++)
      bfr[jt] = *(const bf16x8*)&AwtT[h][jt * 16 + lm][quad * 8];
#pragma unroll
    for (int mt = 0; mt < 8; mt++) {
      bf16x8 a = *(const bf16x8*)(proj_wb +
                    (size_t)(mt * 16 + lm) * CD + h * C_ + quad * 8);
#pragma unroll
      for (int jt = 0; jt < 2; jt++) {
        floatx4 acc = (floatx4){0.f, 0.f, 0.f, 0.f};
        acc = MFMA16(a, bfr[jt], acc);
#pragma unroll
        for (int r = 0; r < 4; r++) {
          int row = quad * 4 + r;
          Mb[(size_t)b * 16384 + (mt * 16 + row) * CD + h * C_ + jt * 16 + lm] =
              f2b(acc[r]);
        }
      }
    }
  }
}

// ---------------------------------------------------------------------------
// K6: out[b] = Mb @ V^T + proj_b. A (Mb) per-ks from global (L2-hot);
// LDS = Bs only, 32,768 B swizzled -> 5 blocks/CU. grid (32, 32), 256 thr.
// ---------------------------------------------------------------------------
__global__ __launch_bounds__(256, 5) void k6_out(
    const unsigned short* __restrict__ vT, const unsigned short* __restrict__ Mb,
    const float* __restrict__ proj_b, float* __restrict__ out)
{
  __shared__ unsigned short Bs[128 * 128];
  const int t = threadIdx.x;
  const int y0 = blockIdx.x * 128, b = blockIdx.y;
  const int wv = t >> 6, l = t & 63, quad = l >> 4, lm = l & 15;

#pragma unroll
  for (int i = 0; i < 8; i++) {
    int f = i * 256 + t;
    int row = f >> 4, ch = f & 15;
    *(uint4*)&Bs[row * 128 + ((ch ^ (row & 15)) << 3)] =
        *(const uint4*)(vT + ((size_t)b * N + y0 + row) * CD + ch * 8);
  }
  __syncthreads();

  floatx4 acc[2][8];
#pragma unroll
  for (int mt = 0; mt < 2; mt++)
#pragma unroll
    for (int nt = 0; nt < 8; nt++) acc[mt][nt] = (floatx4){0.f, 0.f, 0.f, 0.f};

  const unsigned short* mbase =
      Mb + (size_t)b * 16384 + (size_t)(wv * 32 + lm) * CD + quad * 8;
#pragma unroll
  for (int ks = 0; ks < 4; ks++) {
    bf16x8 a0 = *(const bf16x8*)(mbase + ks * 32);
    bf16x8 a1 = *(const bf16x8*)(mbase + 16 * CD + ks * 32);
#pragma unroll
    for (int nt = 0; nt < 8; nt++) {
      bf16x8 bb = *(const bf16x8*)
          &Bs[(nt * 16 + lm) * 128 + (((ks * 4 + quad) ^ lm) << 3)];
      acc[0][nt] = MFMA16(a0, bb, acc[0][nt]);
      acc[1][nt] = MFMA16(a1, bb, acc[1][nt]);
    }
  }

#pragma unroll
  for (int mt = 0; mt < 2; mt++)
#pragma unroll
    for (int r = 0; r < 4; r++) {
      int o = wv * 32 + mt * 16 + quad * 4 + r;
      float pb = proj_b[o];
#pragma unroll
      for (int nt = 0; nt < 8; nt++) {
        int y = y0 + nt * 16 + lm;
        out[((size_t)b * CD + o) * N + y] = acc[mt][nt][r] + pb;
      }
    }
}

extern "C" void kernel_launch(void* const* d_in, const int* in_sizes, int n_in,
                              void* d_out, int out_size, void* d_ws, size_t ws_size,
                              hipStream_t stream)
{
  (void)in_sizes; (void)n_in; (void)out_size; (void)ws_size;
  const float* x           = (const float*)d_in[0];
  const float* qkv_w       = (const float*)d_in[1];
  const float* qkv_b       = (const float*)d_in[2];
  const float* dw_w        = (const float*)d_in[3];
  const float* dw_b        = (const float*)d_in[4];
  const float* proj_w      = (const float*)d_in[5];
  const float* proj_b      = (const float*)d_in[6];
  const float* temperature = (const float*)d_in[7];
  const float* attn_w      = (const float*)d_in[8];
  float* out = (float*)d_out;

  unsigned short* xT      = (unsigned short*)d_ws;   // 16,777,216 sh
  unsigned short* qkv_wb  = xT + (size_t)16777216;   //     49,152
  unsigned short* proj_wb = qkv_wb + 49152;          //     16,384
  unsigned short* qkvd    = proj_wb + 16384;         // 33,554,432 (q,k)
  unsigned short* vT      = qkvd + (size_t)33554432; // 16,777,216
  unsigned short* Mb      = vT + (size_t)16777216;   //    524,288
  float* part = (float*)(Mb + 524288);               //  1,048,576 f

  k0_xt    <<<dim3(64, 4, 32),  256, 0, stream>>>(x, xT);
  k0_w     <<<dim3(64),         256, 0, stream>>>(qkv_w, proj_w, qkv_wb, proj_wb);
  k1_qkv_dw<<<dim3(34, 3, 32),  256, 0, stream>>>(xT, qkv_wb, qkv_b, dw_w, dw_b,
                                                  qkvd, vT);
  k3_gram  <<<dim3(4, H_, B_),  256, 0, stream>>>(qkvd, part);
  k45      <<<dim3(B_),         256, 0, stream>>>(part, proj_wb, temperature,
                                                  attn_w, Mb);
  k6_out   <<<dim3(32, B_),     256, 0, stream>>>(vT, Mb, proj_b, out);
}

// Round 3
// 258.428 us; speedup vs baseline: 1.3670x; 1.1463x over previous
//
#include <hip/hip_runtime.h>

#define B_ 32
#define CD 128
#define O3 384
#define N  4096
#define H_ 4
#define C_ 32

typedef __bf16 bf16x8 __attribute__((ext_vector_type(8)));
typedef float floatx4 __attribute__((ext_vector_type(4)));

#define MFMA16(a, b, c) __builtin_amdgcn_mfma_f32_16x16x32_bf16(a, b, c, 0, 0, 0)

__device__ __forceinline__ float b2f(unsigned int u) {   // low 16 bits
  return __builtin_bit_cast(float, u << 16);
}
__device__ __forceinline__ float b2fh(unsigned int u) {  // high 16 bits
  return __builtin_bit_cast(float, u & 0xffff0000u);
}
__device__ __forceinline__ unsigned short f2b(float f) {
  unsigned int bits = __builtin_bit_cast(unsigned int, f);
  unsigned int r = (bits + 0x7FFFu + ((bits >> 16) & 1u)) >> 16;
  return (unsigned short)r;
}

// ---------------------------------------------------------------------------
// K0a: transpose+convert x [b][c][n] fp32 -> xT [b][n][c] bf16.
// (round-0 version: stride 68 keeps float4 LDS writes 16B-aligned)
// ---------------------------------------------------------------------------
__global__ __launch_bounds__(256) void k0_xt(const float* __restrict__ x,
                                             unsigned short* __restrict__ xT)
{
  __shared__ float xt[32 * 68];
  const int t = threadIdx.x;
  const int n0 = blockIdx.x * 64, c0 = blockIdx.y * 32, b = blockIdx.z;
  const float* xb = x + ((size_t)b * CD + c0) * N + n0;
#pragma unroll
  for (int i = 0; i < 2; i++) {
    int f = i * 256 + t;
    int c = f >> 4, n4 = (f & 15) * 4;
    float4 v = *(const float4*)(xb + (size_t)c * N + n4);
    *(float4*)&xt[c * 68 + n4] = v;
  }
  __syncthreads();
  int n = t >> 2, cb = (t & 3) * 8;
  unsigned short tmp[8];
#pragma unroll
  for (int j = 0; j < 8; j++) tmp[j] = f2b(xt[(cb + j) * 68 + n]);
  *(uint4*)(xT + ((size_t)b * N + n0 + n) * CD + c0 + cb) = *(uint4*)tmp;
}

// ---------------------------------------------------------------------------
// K0b: qkv_w and proj_w fp32 -> bf16, plus packed depthwise table
// dwq[o] = {w0, w1, w2, dw_b[o]} (taps = column 1 of the 3x3 kernel).
// grid 66 x 256.
// ---------------------------------------------------------------------------
__global__ void k0_w(const float* __restrict__ qkv_w,
                     const float* __restrict__ proj_w,
                     const float* __restrict__ dw_w,
                     const float* __restrict__ dw_b,
                     unsigned short* __restrict__ qkv_wb,
                     unsigned short* __restrict__ proj_wb,
                     float4* __restrict__ dwq)
{
  int e = (blockIdx.x * 256 + threadIdx.x) * 4;
  if (e < 49152) {
    float4 v = *(const float4*)(qkv_w + e);
    unsigned short tmp[4] = {f2b(v.x), f2b(v.y), f2b(v.z), f2b(v.w)};
    *(uint2*)(qkv_wb + e) = *(uint2*)tmp;
  } else if (e < 65536) {
    int off = e - 49152;
    float4 v = *(const float4*)(proj_w + off);
    unsigned short tmp[4] = {f2b(v.x), f2b(v.y), f2b(v.z), f2b(v.w)};
    *(uint2*)(proj_wb + off) = *(uint2*)tmp;
  } else {
    int o = (e - 65536) >> 2;
    if (o < 384)
      dwq[o] = make_float4(dw_w[o * 9 + 1], dw_w[o * 9 + 4],
                           dw_w[o * 9 + 7], dw_b[o]);
  }
}

// ---------------------------------------------------------------------------
// K1: MFMA GEMM (128o x 124y outputs, 128 staged rows incl. 2+2 halo, K=128)
// + bias + 3-tap depthwise + bias. Round-0 structure with 3 latency fixes:
//  - grid (3,34,32): otile fastest -> the 3 blocks sharing one xT tile are
//    dispatched adjacently -> L2/L3 hits instead of HBM re-fetch.
//  - weight fragments (8 x bf16x8 = 32 VGPR) hoisted before the staging
//    barrier -> MFMA loop is purely LDS-fed, weight L2 latency hidden.
//  - epilogues read packed dwq float4 (1 load) instead of 4 scalar loads.
// LDS 34,816 B -> 4 blocks/CU. q,k -> qkvd[b][o2][n]; v -> vT[b][n][c].
// ---------------------------------------------------------------------------
__global__ __launch_bounds__(256, 4) void k1_qkv_dw(
    const unsigned short* __restrict__ xT, const unsigned short* __restrict__ qkv_wb,
    const float* __restrict__ qkv_b, const float4* __restrict__ dwq,
    unsigned short* __restrict__ qkvd, unsigned short* __restrict__ vT)
{
  __shared__ __align__(16) char smem[34816];
  unsigned short* Bs   = (unsigned short*)smem;   // [128][136] staged x rows
  unsigned short* pres = (unsigned short*)smem;   // bf16 pre-dw tile (alias)

  const int t = threadIdx.x;
  const int otile = blockIdx.x, ytile = blockIdx.y, b = blockIdx.z;
  const int obase = otile * 128;
  const int ybase = ytile * 124;                  // first output y (even)
  const int wv = t >> 6, l = t & 63, quad = l >> 4, lm = l & 15;

  // hoist A-operand (weights) into registers; latency hides under staging
  const unsigned short* wbase =
      qkv_wb + (size_t)(obase + wv * 32 + lm) * CD + quad * 8;
  bf16x8 wa0[4], wa1[4];
#pragma unroll
  for (int ks = 0; ks < 4; ks++) {
    wa0[ks] = *(const bf16x8*)(wbase + ks * 32);
    wa1[ks] = *(const bf16x8*)(wbase + 16 * CD + ks * 32);
  }

  // stage B: rows i=0..127 <-> y = ybase-2+i (zero outside [0,N));
  // interior ytiles (1..32) take the unguarded path
  if (ytile >= 1 && ytile <= 32) {
#pragma unroll
    for (int i = 0; i < 8; i++) {
      int f = i * 256 + t;
      int row = f >> 4, c8 = (f & 15) * 8;
      *(uint4*)&Bs[row * 136 + c8] =
          *(const uint4*)(xT + ((size_t)b * N + ybase - 2 + row) * CD + c8);
    }
  } else {
#pragma unroll
    for (int i = 0; i < 8; i++) {
      int f = i * 256 + t;
      int row = f >> 4, c8 = (f & 15) * 8;
      int yg = ybase - 2 + row;
      uint4 v = make_uint4(0u, 0u, 0u, 0u);
      if (yg >= 0 && yg < N)
        v = *(const uint4*)(xT + ((size_t)b * N + yg) * CD + c8);
      *(uint4*)&Bs[row * 136 + c8] = v;
    }
  }
  __syncthreads();

  floatx4 acc[2][8];
#pragma unroll
  for (int mt = 0; mt < 2; mt++)
#pragma unroll
    for (int nt = 0; nt < 8; nt++) acc[mt][nt] = (floatx4){0.f, 0.f, 0.f, 0.f};

#pragma unroll
  for (int ks = 0; ks < 4; ks++) {
#pragma unroll
    for (int nt = 0; nt < 8; nt++) {
      bf16x8 bb = *(const bf16x8*)&Bs[(nt * 16 + lm) * 136 + ks * 32 + quad * 8];
      acc[0][nt] = MFMA16(wa0[ks], bb, acc[0][nt]);
      acc[1][nt] = MFMA16(wa1[ks], bb, acc[1][nt]);
    }
  }

  if (otile < 2) {
    // ---- q,k: pres[o][j] (j = local row - 1, j in [0,126]), stride 132
    __syncthreads();
#pragma unroll
    for (int mt = 0; mt < 2; mt++)
#pragma unroll
      for (int r = 0; r < 4; r++) {
        int o = wv * 32 + mt * 16 + quad * 4 + r;
        float bias = qkv_b[obase + o];
#pragma unroll
        for (int nt = 0; nt < 8; nt++) {
          int i = nt * 16 + lm;
          if (i >= 1) {
            int yg = ybase - 2 + i;
            pres[o * 132 + (i - 1)] =
                f2b((yg >= 0 && yg < N) ? (acc[mt][nt][r] + bias) : 0.f);
          }
        }
      }
    __syncthreads();
    // y-pair sweep: wave-uniform o, lanes cover 62 aligned pairs
    const int p = t & 63, og = t >> 6;
    const bool ok = (p < 62) && (ybase + 2 * p < N);
    const unsigned int* presu = (const unsigned int*)pres;  // pairs of bf16
    for (int r2 = 0; r2 < 32; r2++) {
      int oo = __builtin_amdgcn_readfirstlane(obase + og * 32 + r2);
      float4 wq = dwq[oo];                        // {w0,w1,w2,db} s_load x4
      int o = oo - obase;
      unsigned int u0 = presu[(o * 132 >> 1) + p];
      unsigned int u1 = presu[(o * 132 >> 1) + p + 1];
      float v0 = b2f(u0), v1 = b2fh(u0), v2 = b2f(u1), v3 = b2fh(u1);
      float out0 = wq.x * v0 + wq.y * v1 + wq.z * v2 + wq.w;
      float out1 = wq.x * v1 + wq.y * v2 + wq.z * v3 + wq.w;
      unsigned int pk = (unsigned int)f2b(out0) |
                        ((unsigned int)f2b(out1) << 16);
      if (ok)
        *(unsigned int*)(qkvd + ((size_t)b * 256 + oo) * N + ybase + 2 * p) = pk;
    }
  } else {
    // ---- v: pres[i][o], stride 132; per-lane o, sliding window over y
    const int o = t & 127, half = t >> 7;
    const int oo = obase + o;
    const float4 wq = dwq[oo];                    // {w0,w1,w2,db}
    __syncthreads();
#pragma unroll
    for (int mt = 0; mt < 2; mt++)
#pragma unroll
      for (int r = 0; r < 4; r++) {
        int o2 = wv * 32 + mt * 16 + quad * 4 + r;
        float bias = qkv_b[obase + o2];
#pragma unroll
        for (int nt = 0; nt < 8; nt++) {
          int i = nt * 16 + lm;
          int yg = ybase - 2 + i;
          pres[i * 132 + o2] =
              f2b((yg >= 0 && yg < N) ? (acc[mt][nt][r] + bias) : 0.f);
        }
      }
    __syncthreads();
    int i0 = 2 + half * 62;                     // halves: i 2..63, 64..125
    float pm = b2f((unsigned int)pres[(i0 - 1) * 132 + o]);
    float pc = b2f((unsigned int)pres[i0 * 132 + o]);
    for (int i = i0; i < i0 + 62; i++) {
      float pp = b2f((unsigned int)pres[(i + 1) * 132 + o]);
      int yo = ybase - 2 + i;
      if (yo < N) {
        float v = wq.x * pm + wq.y * pc + wq.z * pp + wq.w;
        vT[((size_t)b * N + yo) * CD + o] = f2b(v);
      }
      pm = pc; pc = pp;
    }
  }
}

// ---------------------------------------------------------------------------
// K3: MFMA Gram, fragments loaded straight from global (K-major layout),
// no staging barriers. 32x32 QK^T partial over 1024 n + Q/K norms via
// self-MFMA diagonals. part[b][h][ns][2048]. grid (4, H, B), 256 thr.
// ---------------------------------------------------------------------------
__global__ __launch_bounds__(256, 4) void k3_gram(
    const unsigned short* __restrict__ qkvd, float* __restrict__ part)
{
  __shared__ float red[4 * 8 * 272];   // [wv][tile][row*17+col]
  const int ns = blockIdx.x, h = blockIdx.y, b = blockIdx.z;
  const int t = threadIdx.x;
  const int wv = t >> 6, l = t & 63, quad = l >> 4, lm = l & 15;
  const unsigned short* qb = qkvd + ((size_t)b * 256 + h * C_) * N;
  const unsigned short* kb = qkvd + ((size_t)b * 256 + 128 + h * C_) * N;

  floatx4 acc[8];
#pragma unroll
  for (int i = 0; i < 8; i++) acc[i] = (floatx4){0.f, 0.f, 0.f, 0.f};

  const int nbase = ns * 1024 + wv * 32 + quad * 8;
#pragma unroll
  for (int ch = 0; ch < 8; ch++) {
    int nc = nbase + ch * 128;
    bf16x8 a0 = *(const bf16x8*)(qb + (size_t)lm * N + nc);
    bf16x8 a1 = *(const bf16x8*)(qb + (size_t)(16 + lm) * N + nc);
    bf16x8 b0 = *(const bf16x8*)(kb + (size_t)lm * N + nc);
    bf16x8 b1 = *(const bf16x8*)(kb + (size_t)(16 + lm) * N + nc);
    acc[0] = MFMA16(a0, b0, acc[0]);
    acc[1] = MFMA16(a0, b1, acc[1]);
    acc[2] = MFMA16(a1, b0, acc[2]);
    acc[3] = MFMA16(a1, b1, acc[3]);
    acc[4] = MFMA16(a0, a0, acc[4]);
    acc[5] = MFMA16(a1, a1, acc[5]);
    acc[6] = MFMA16(b0, b0, acc[6]);
    acc[7] = MFMA16(b1, b1, acc[7]);
  }

#pragma unroll
  for (int tl = 0; tl < 8; tl++)
#pragma unroll
    for (int r = 0; r < 4; r++)
      red[wv * 2176 + tl * 272 + (quad * 4 + r) * 17 + lm] = acc[tl][r];
  __syncthreads();

  float* pb = part + ((size_t)(b * H_ + h) * 4 + ns) * 2048;
  for (int e = t; e < 2048; e += 256) {
    int tl = e >> 8, rc = e & 255, row = rc >> 4, col = rc & 15;
    int a = tl * 272 + row * 17 + col;
    float s = red[a] + red[2176 + a] + red[2 * 2176 + a] + red[3 * 2176 + a];
    if (tl < 4) {
      int mt = tl >> 1, nt = tl & 1;
      pb[(mt * 16 + row) * 32 + nt * 16 + col] = s;
    } else if (row == col) {
      if (tl < 6) pb[1024 + (tl - 4) * 16 + row] = s;
      else        pb[1056 + (tl - 6) * 16 + row] = s;
    }
  }
}

// ---------------------------------------------------------------------------
// K45: sum partials, normalize+temperature, exact stable top-k ranks, fold
// 4 masked softmaxes -> AwtT bf16; M = proj_w @ blockdiag(A) via MFMA.
// grid (B), 256 thr.
// ---------------------------------------------------------------------------
__global__ __launch_bounds__(256) void k45(
    const float* __restrict__ part, const unsigned short* __restrict__ proj_wb,
    const float* __restrict__ temperature, const float* __restrict__ attn_w,
    unsigned short* __restrict__ Mb)
{
  __shared__ float La[H_][C_][33];
  __shared__ float sq2[256];
  __shared__ float rn[256];
  __shared__ float exL[H_][C_][33];
  __shared__ unsigned char rkL[H_][C_][C_];
  __shared__ unsigned short AwtT[H_][C_][40];
  const int b = blockIdx.x, t = threadIdx.x;

  const float* pbb = part + (size_t)b * 32768;
  for (int e = t; e < 4 * 2048; e += 256) {
    int h = e >> 11, idx = e & 2047;
    if (idx < 1088) {
      const float* p = pbb + h * 8192 + idx;
      float s = p[0] + p[2048] + p[2 * 2048] + p[3 * 2048];
      if (idx < 1024) La[h][idx >> 5][idx & 31] = s;
      else if (idx < 1056) sq2[h * 32 + (idx - 1024)] = s;
      else sq2[128 + h * 32 + (idx - 1056)] = s;
    }
  }
  __syncthreads();
  rn[t] = 1.f / fmaxf(sqrtf(sq2[t]), 1e-12f);
  __syncthreads();
  for (int e = t; e < 4096; e += 256) {
    int h = e >> 10, i = (e >> 5) & 31, j = e & 31;
    La[h][i][j] *= rn[h * 32 + i] * rn[128 + h * 32 + j] * temperature[h];
  }
  __syncthreads();

  if (t < 128) {
    int h = t >> 5, i = t & 31;
    float m = -1e30f;
    for (int j = 0; j < 32; j++) m = fmaxf(m, La[h][i][j]);
    float S0 = 0.f, S1 = 0.f, S2 = 0.f, S3 = 0.f;
    for (int j = 0; j < 32; j++) {
      float vj = La[h][i][j];
      int r = 0;
      for (int j2 = 0; j2 < 32; j2++) {
        float v2 = La[h][i][j2];
        r += (v2 > vj) || (v2 == vj && j2 < j);
      }
      float e = __expf(vj - m);
      exL[h][i][j] = e;
      rkL[h][i][j] = (unsigned char)r;
      if (r < 16) S0 += e;
      if (r < 21) S1 += e;
      if (r < 24) S2 += e;
      if (r < 25) S3 += e;
    }
    float w0 = attn_w[0] / S0, w1 = attn_w[1] / S1;
    float w2 = attn_w[2] / S2, w3 = attn_w[3] / S3;
    for (int j = 0; j < 32; j++) {
      int r = rkL[h][i][j];
      float cmb = (r < 16 ? w0 : 0.f) + (r < 21 ? w1 : 0.f) +
                  (r < 24 ? w2 : 0.f) + (r < 25 ? w3 : 0.f);
      AwtT[h][j][i] = f2b(exL[h][i][j] * cmb);
    }
  }
  __syncthreads();

  {
    const int wv = t >> 6, l = t & 63, quad = l >> 4, lm = l & 15;
    const int h = wv;
    bf16x8 bfr[2];
#pragma unroll
    for (int jt = 0; jt < 2; jt++)
      bfr[jt] = *(const bf16x8*)&AwtT[h][jt * 16 + lm][quad * 8];
#pragma unroll
    for (int mt = 0; mt < 8; mt++) {
      bf16x8 a = *(const bf16x8*)(proj_wb +
                    (size_t)(mt * 16 + lm) * CD + h * C_ + quad * 8);
#pragma unroll
      for (int jt = 0; jt < 2; jt++) {
        floatx4 acc = (floatx4){0.f, 0.f, 0.f, 0.f};
        acc = MFMA16(a, bfr[jt], acc);
#pragma unroll
        for (int r = 0; r < 4; r++) {
          int row = quad * 4 + r;
          Mb[(size_t)b * 16384 + (mt * 16 + row) * CD + h * C_ + jt * 16 + lm] =
              f2b(acc[r]);
        }
      }
    }
  }
}

// ---------------------------------------------------------------------------
// K6: out[b] = Mb @ V^T + proj_b. A fragments (Mb, L2-hot) hoisted into
// registers before the staging barrier. LDS = Bs only -> 4 blocks/CU.
// grid (32, 32), 256 thr.
// ---------------------------------------------------------------------------
__global__ __launch_bounds__(256, 4) void k6_out(
    const unsigned short* __restrict__ vT, const unsigned short* __restrict__ Mb,
    const float* __restrict__ proj_b, float* __restrict__ out)
{
  __shared__ unsigned short Bs[128 * 136];
  const int t = threadIdx.x;
  const int y0 = blockIdx.x * 128, b = blockIdx.y;
  const int wv = t >> 6, l = t & 63, quad = l >> 4, lm = l & 15;

  const unsigned short* mbase =
      Mb + (size_t)b * 16384 + (size_t)(wv * 32 + lm) * CD + quad * 8;
  bf16x8 ma0[4], ma1[4];
#pragma unroll
  for (int ks = 0; ks < 4; ks++) {
    ma0[ks] = *(const bf16x8*)(mbase + ks * 32);
    ma1[ks] = *(const bf16x8*)(mbase + 16 * CD + ks * 32);
  }

#pragma unroll
  for (int i = 0; i < 8; i++) {
    int f = i * 256 + t;
    int row = f >> 4, c8 = (f & 15) * 8;
    *(uint4*)&Bs[row * 136 + c8] =
        *(const uint4*)(vT + ((size_t)b * N + y0 + row) * CD + c8);
  }
  __syncthreads();

  floatx4 acc[2][8];
#pragma unroll
  for (int mt = 0; mt < 2; mt++)
#pragma unroll
    for (int nt = 0; nt < 8; nt++) acc[mt][nt] = (floatx4){0.f, 0.f, 0.f, 0.f};

#pragma unroll
  for (int ks = 0; ks < 4; ks++) {
#pragma unroll
    for (int nt = 0; nt < 8; nt++) {
      bf16x8 bb = *(const bf16x8*)&Bs[(nt * 16 + lm) * 136 + ks * 32 + quad * 8];
      acc[0][nt] = MFMA16(ma0[ks], bb, acc[0][nt]);
      acc[1][nt] = MFMA16(ma1[ks], bb, acc[1][nt]);
    }
  }

#pragma unroll
  for (int mt = 0; mt < 2; mt++)
#pragma unroll
    for (int r = 0; r < 4; r++) {
      int o = wv * 32 + mt * 16 + quad * 4 + r;
      float pb = proj_b[o];
#pragma unroll
      for (int nt = 0; nt < 8; nt++) {
        int y = y0 + nt * 16 + lm;
        out[((size_t)b * CD + o) * N + y] = acc[mt][nt][r] + pb;
      }
    }
}

extern "C" void kernel_launch(void* const* d_in, const int* in_sizes, int n_in,
                              void* d_out, int out_size, void* d_ws, size_t ws_size,
                              hipStream_t stream)
{
  (void)in_sizes; (void)n_in; (void)out_size; (void)ws_size;
  const float* x           = (const float*)d_in[0];
  const float* qkv_w       = (const float*)d_in[1];
  const float* qkv_b       = (const float*)d_in[2];
  const float* dw_w        = (const float*)d_in[3];
  const float* dw_b        = (const float*)d_in[4];
  const float* proj_w      = (const float*)d_in[5];
  const float* proj_b      = (const float*)d_in[6];
  const float* temperature = (const float*)d_in[7];
  const float* attn_w      = (const float*)d_in[8];
  float* out = (float*)d_out;

  unsigned short* xT      = (unsigned short*)d_ws;   // 16,777,216 sh
  unsigned short* qkv_wb  = xT + (size_t)16777216;   //     49,152
  unsigned short* proj_wb = qkv_wb + 49152;          //     16,384
  unsigned short* qkvd    = proj_wb + 16384;         // 33,554,432 (q,k)
  unsigned short* vT      = qkvd + (size_t)33554432; // 16,777,216
  unsigned short* Mb      = vT + (size_t)16777216;   //    524,288
  float* part = (float*)(Mb + 524288);               //  1,048,576 f
  // dwq (384 float4 = 6 KiB) aliases Mb: written by k0_w, read by k1,
  // dead before k45 writes Mb. 16B-aligned (Mb offset is 16B-multiple).
  float4* dwq = (float4*)Mb;

  k0_xt    <<<dim3(64, 4, 32),  256, 0, stream>>>(x, xT);
  k0_w     <<<dim3(66),         256, 0, stream>>>(qkv_w, proj_w, dw_w, dw_b,
                                                  qkv_wb, proj_wb, dwq);
  k1_qkv_dw<<<dim3(3, 34, 32),  256, 0, stream>>>(xT, qkv_wb, qkv_b, dwq,
                                                  qkvd, vT);
  k3_gram  <<<dim3(4, H_, B_),  256, 0, stream>>>(qkvd, part);
  k45      <<<dim3(B_),         256, 0, stream>>>(part, proj_wb, temperature,
                                                  attn_w, Mb);
  k6_out   <<<dim3(32, B_),     256, 0, stream>>>(vT, Mb, proj_b, out);
}

// Round 4
// 255.482 us; speedup vs baseline: 1.3827x; 1.0115x over previous
//
#include <hip/hip_runtime.h>

#define B_ 32
#define CD 128
#define O3 384
#define N  4096
#define H_ 4
#define C_ 32

typedef __bf16 bf16x8 __attribute__((ext_vector_type(8)));
typedef float floatx4 __attribute__((ext_vector_type(4)));

#define MFMA16(a, b, c) __builtin_amdgcn_mfma_f32_16x16x32_bf16(a, b, c, 0, 0, 0)

__device__ __forceinline__ float b2f(unsigned int u) {   // low 16 bits
  return __builtin_bit_cast(float, u << 16);
}
__device__ __forceinline__ float b2fh(unsigned int u) {  // high 16 bits
  return __builtin_bit_cast(float, u & 0xffff0000u);
}
__device__ __forceinline__ unsigned short f2b(float f) {
  unsigned int bits = __builtin_bit_cast(unsigned int, f);
  unsigned int r = (bits + 0x7FFFu + ((bits >> 16) & 1u)) >> 16;
  return (unsigned short)r;
}

// ---------------------------------------------------------------------------
// K0a: transpose+convert x [b][c][n] fp32 -> xT [b][n][c] bf16.
// LDS stride 66 (f32): phase-2 read banks (cb*66 mod 32 = {0,16,0,16})
// -> 2-way conflict (free) vs 4-way at stride 68. float2 writes keep 8B
// alignment (row stride 264 B).
// ---------------------------------------------------------------------------
__global__ __launch_bounds__(256) void k0_xt(const float* __restrict__ x,
                                             unsigned short* __restrict__ xT)
{
  __shared__ float xt[32 * 66];
  const int t = threadIdx.x;
  const int n0 = blockIdx.x * 64, c0 = blockIdx.y * 32, b = blockIdx.z;
  const float* xb = x + ((size_t)b * CD + c0) * N + n0;
#pragma unroll
  for (int i = 0; i < 2; i++) {
    int f = i * 256 + t;
    int c = f >> 4, n4 = (f & 15) * 4;
    float4 v = *(const float4*)(xb + (size_t)c * N + n4);
    *(float2*)&xt[c * 66 + n4]     = make_float2(v.x, v.y);
    *(float2*)&xt[c * 66 + n4 + 2] = make_float2(v.z, v.w);
  }
  __syncthreads();
  int n = t >> 2, cb = (t & 3) * 8;
  unsigned short tmp[8];
#pragma unroll
  for (int j = 0; j < 8; j++) tmp[j] = f2b(xt[(cb + j) * 66 + n]);
  *(uint4*)(xT + ((size_t)b * N + n0 + n) * CD + c0 + cb) = *(uint4*)tmp;
}

// ---------------------------------------------------------------------------
// K0b: qkv_w and proj_w fp32 -> bf16, plus packed depthwise table
// dwq[o] = {w0, w1, w2, dw_b[o]} (taps = column 1 of the 3x3 kernel).
// grid 66 x 256.
// ---------------------------------------------------------------------------
__global__ void k0_w(const float* __restrict__ qkv_w,
                     const float* __restrict__ proj_w,
                     const float* __restrict__ dw_w,
                     const float* __restrict__ dw_b,
                     unsigned short* __restrict__ qkv_wb,
                     unsigned short* __restrict__ proj_wb,
                     float4* __restrict__ dwq)
{
  int e = (blockIdx.x * 256 + threadIdx.x) * 4;
  if (e < 49152) {
    float4 v = *(const float4*)(qkv_w + e);
    unsigned short tmp[4] = {f2b(v.x), f2b(v.y), f2b(v.z), f2b(v.w)};
    *(uint2*)(qkv_wb + e) = *(uint2*)tmp;
  } else if (e < 65536) {
    int off = e - 49152;
    float4 v = *(const float4*)(proj_w + off);
    unsigned short tmp[4] = {f2b(v.x), f2b(v.y), f2b(v.z), f2b(v.w)};
    *(uint2*)(proj_wb + off) = *(uint2*)tmp;
  } else {
    int o = (e - 65536) >> 2;
    if (o < 384)
      dwq[o] = make_float4(dw_w[o * 9 + 1], dw_w[o * 9 + 4],
                           dw_w[o * 9 + 7], dw_b[o]);
  }
}

// ---------------------------------------------------------------------------
// K1: MFMA GEMM (128o x 124y outputs, 128 staged rows incl. 2+2 halo, K=128)
// + bias + 3-tap depthwise + bias. Round-3 version (proven 55 us):
//  - grid (3,34,32): otile fastest -> the 3 blocks sharing one xT tile are
//    dispatched adjacently -> L2/L3 hits instead of HBM re-fetch.
//  - weight fragments (8 x bf16x8 = 32 VGPR) hoisted before the staging
//    barrier -> MFMA loop is purely LDS-fed, weight L2 latency hidden.
//  - epilogues read packed dwq float4 (1 load) instead of 4 scalar loads.
// LDS 34,816 B -> 4 blocks/CU. q,k -> qkvd[b][o2][n]; v -> vT[b][n][c].
// ---------------------------------------------------------------------------
__global__ __launch_bounds__(256, 4) void k1_qkv_dw(
    const unsigned short* __restrict__ xT, const unsigned short* __restrict__ qkv_wb,
    const float* __restrict__ qkv_b, const float4* __restrict__ dwq,
    unsigned short* __restrict__ qkvd, unsigned short* __restrict__ vT)
{
  __shared__ __align__(16) char smem[34816];
  unsigned short* Bs   = (unsigned short*)smem;   // [128][136] staged x rows
  unsigned short* pres = (unsigned short*)smem;   // bf16 pre-dw tile (alias)

  const int t = threadIdx.x;
  const int otile = blockIdx.x, ytile = blockIdx.y, b = blockIdx.z;
  const int obase = otile * 128;
  const int ybase = ytile * 124;                  // first output y (even)
  const int wv = t >> 6, l = t & 63, quad = l >> 4, lm = l & 15;

  // hoist A-operand (weights) into registers; latency hides under staging
  const unsigned short* wbase =
      qkv_wb + (size_t)(obase + wv * 32 + lm) * CD + quad * 8;
  bf16x8 wa0[4], wa1[4];
#pragma unroll
  for (int ks = 0; ks < 4; ks++) {
    wa0[ks] = *(const bf16x8*)(wbase + ks * 32);
    wa1[ks] = *(const bf16x8*)(wbase + 16 * CD + ks * 32);
  }

  // stage B: rows i=0..127 <-> y = ybase-2+i (zero outside [0,N));
  // interior ytiles (1..32) take the unguarded path
  if (ytile >= 1 && ytile <= 32) {
#pragma unroll
    for (int i = 0; i < 8; i++) {
      int f = i * 256 + t;
      int row = f >> 4, c8 = (f & 15) * 8;
      *(uint4*)&Bs[row * 136 + c8] =
          *(const uint4*)(xT + ((size_t)b * N + ybase - 2 + row) * CD + c8);
    }
  } else {
#pragma unroll
    for (int i = 0; i < 8; i++) {
      int f = i * 256 + t;
      int row = f >> 4, c8 = (f & 15) * 8;
      int yg = ybase - 2 + row;
      uint4 v = make_uint4(0u, 0u, 0u, 0u);
      if (yg >= 0 && yg < N)
        v = *(const uint4*)(xT + ((size_t)b * N + yg) * CD + c8);
      *(uint4*)&Bs[row * 136 + c8] = v;
    }
  }
  __syncthreads();

  floatx4 acc[2][8];
#pragma unroll
  for (int mt = 0; mt < 2; mt++)
#pragma unroll
    for (int nt = 0; nt < 8; nt++) acc[mt][nt] = (floatx4){0.f, 0.f, 0.f, 0.f};

#pragma unroll
  for (int ks = 0; ks < 4; ks++) {
#pragma unroll
    for (int nt = 0; nt < 8; nt++) {
      bf16x8 bb = *(const bf16x8*)&Bs[(nt * 16 + lm) * 136 + ks * 32 + quad * 8];
      acc[0][nt] = MFMA16(wa0[ks], bb, acc[0][nt]);
      acc[1][nt] = MFMA16(wa1[ks], bb, acc[1][nt]);
    }
  }

  if (otile < 2) {
    // ---- q,k: pres[o][j] (j = local row - 1, j in [0,126]), stride 132
    __syncthreads();
#pragma unroll
    for (int mt = 0; mt < 2; mt++)
#pragma unroll
      for (int r = 0; r < 4; r++) {
        int o = wv * 32 + mt * 16 + quad * 4 + r;
        float bias = qkv_b[obase + o];
#pragma unroll
        for (int nt = 0; nt < 8; nt++) {
          int i = nt * 16 + lm;
          if (i >= 1) {
            int yg = ybase - 2 + i;
            pres[o * 132 + (i - 1)] =
                f2b((yg >= 0 && yg < N) ? (acc[mt][nt][r] + bias) : 0.f);
          }
        }
      }
    __syncthreads();
    // y-pair sweep: wave-uniform o, lanes cover 62 aligned pairs
    const int p = t & 63, og = t >> 6;
    const bool ok = (p < 62) && (ybase + 2 * p < N);
    const unsigned int* presu = (const unsigned int*)pres;  // pairs of bf16
    for (int r2 = 0; r2 < 32; r2++) {
      int oo = __builtin_amdgcn_readfirstlane(obase + og * 32 + r2);
      float4 wq = dwq[oo];                        // {w0,w1,w2,db} s_load x4
      int o = oo - obase;
      unsigned int u0 = presu[(o * 132 >> 1) + p];
      unsigned int u1 = presu[(o * 132 >> 1) + p + 1];
      float v0 = b2f(u0), v1 = b2fh(u0), v2 = b2f(u1), v3 = b2fh(u1);
      float out0 = wq.x * v0 + wq.y * v1 + wq.z * v2 + wq.w;
      float out1 = wq.x * v1 + wq.y * v2 + wq.z * v3 + wq.w;
      unsigned int pk = (unsigned int)f2b(out0) |
                        ((unsigned int)f2b(out1) << 16);
      if (ok)
        *(unsigned int*)(qkvd + ((size_t)b * 256 + oo) * N + ybase + 2 * p) = pk;
    }
  } else {
    // ---- v: pres[i][o], stride 132; per-lane o, sliding window over y
    const int o = t & 127, half = t >> 7;
    const int oo = obase + o;
    const float4 wq = dwq[oo];                    // {w0,w1,w2,db}
    __syncthreads();
#pragma unroll
    for (int mt = 0; mt < 2; mt++)
#pragma unroll
      for (int r = 0; r < 4; r++) {
        int o2 = wv * 32 + mt * 16 + quad * 4 + r;
        float bias = qkv_b[obase + o2];
#pragma unroll
        for (int nt = 0; nt < 8; nt++) {
          int i = nt * 16 + lm;
          int yg = ybase - 2 + i;
          pres[i * 132 + o2] =
              f2b((yg >= 0 && yg < N) ? (acc[mt][nt][r] + bias) : 0.f);
        }
      }
    __syncthreads();
    int i0 = 2 + half * 62;                     // halves: i 2..63, 64..125
    float pm = b2f((unsigned int)pres[(i0 - 1) * 132 + o]);
    float pc = b2f((unsigned int)pres[i0 * 132 + o]);
    for (int i = i0; i < i0 + 62; i++) {
      float pp = b2f((unsigned int)pres[(i + 1) * 132 + o]);
      int yo = ybase - 2 + i;
      if (yo < N) {
        float v = wq.x * pm + wq.y * pc + wq.z * pp + wq.w;
        vT[((size_t)b * N + yo) * CD + o] = f2b(v);
      }
      pm = pc; pc = pp;
    }
  }
}

// ---------------------------------------------------------------------------
// K3: MFMA Gram, fragments loaded straight from global (K-major layout),
// no staging barriers. 32x32 QK^T partial over 1024 n + Q/K norms via
// self-MFMA diagonals. part[b][h][ns][2048]. grid (4, H, B), 256 thr.
// ---------------------------------------------------------------------------
__global__ __launch_bounds__(256, 4) void k3_gram(
    const unsigned short* __restrict__ qkvd, float* __restrict__ part)
{
  __shared__ float red[4 * 8 * 272];   // [wv][tile][row*17+col]
  const int ns = blockIdx.x, h = blockIdx.y, b = blockIdx.z;
  const int t = threadIdx.x;
  const int wv = t >> 6, l = t & 63, quad = l >> 4, lm = l & 15;
  const unsigned short* qb = qkvd + ((size_t)b * 256 + h * C_) * N;
  const unsigned short* kb = qkvd + ((size_t)b * 256 + 128 + h * C_) * N;

  floatx4 acc[8];
#pragma unroll
  for (int i = 0; i < 8; i++) acc[i] = (floatx4){0.f, 0.f, 0.f, 0.f};

  const int nbase = ns * 1024 + wv * 32 + quad * 8;
#pragma unroll
  for (int ch = 0; ch < 8; ch++) {
    int nc = nbase + ch * 128;
    bf16x8 a0 = *(const bf16x8*)(qb + (size_t)lm * N + nc);
    bf16x8 a1 = *(const bf16x8*)(qb + (size_t)(16 + lm) * N + nc);
    bf16x8 b0 = *(const bf16x8*)(kb + (size_t)lm * N + nc);
    bf16x8 b1 = *(const bf16x8*)(kb + (size_t)(16 + lm) * N + nc);
    acc[0] = MFMA16(a0, b0, acc[0]);
    acc[1] = MFMA16(a0, b1, acc[1]);
    acc[2] = MFMA16(a1, b0, acc[2]);
    acc[3] = MFMA16(a1, b1, acc[3]);
    acc[4] = MFMA16(a0, a0, acc[4]);
    acc[5] = MFMA16(a1, a1, acc[5]);
    acc[6] = MFMA16(b0, b0, acc[6]);
    acc[7] = MFMA16(b1, b1, acc[7]);
  }

#pragma unroll
  for (int tl = 0; tl < 8; tl++)
#pragma unroll
    for (int r = 0; r < 4; r++)
      red[wv * 2176 + tl * 272 + (quad * 4 + r) * 17 + lm] = acc[tl][r];
  __syncthreads();

  float* pb = part + ((size_t)(b * H_ + h) * 4 + ns) * 2048;
  for (int e = t; e < 2048; e += 256) {
    int tl = e >> 8, rc = e & 255, row = rc >> 4, col = rc & 15;
    int a = tl * 272 + row * 17 + col;
    float s = red[a] + red[2176 + a] + red[2 * 2176 + a] + red[3 * 2176 + a];
    if (tl < 4) {
      int mt = tl >> 1, nt = tl & 1;
      pb[(mt * 16 + row) * 32 + nt * 16 + col] = s;
    } else if (row == col) {
      if (tl < 6) pb[1024 + (tl - 4) * 16 + row] = s;
      else        pb[1056 + (tl - 6) * 16 + row] = s;
    }
  }
}

// ---------------------------------------------------------------------------
// K45: sum partials, normalize+temperature, exact stable top-k ranks, fold
// 4 masked softmaxes -> AwtT bf16; M = proj_w @ blockdiag(A) via MFMA.
// grid (B), 256 thr.
// ---------------------------------------------------------------------------
__global__ __launch_bounds__(256) void k45(
    const float* __restrict__ part, const unsigned short* __restrict__ proj_wb,
    const float* __restrict__ temperature, const float* __restrict__ attn_w,
    unsigned short* __restrict__ Mb)
{
  __shared__ float La[H_][C_][33];
  __shared__ float sq2[256];
  __shared__ float rn[256];
  __shared__ float exL[H_][C_][33];
  __shared__ unsigned char rkL[H_][C_][C_];
  __shared__ unsigned short AwtT[H_][C_][40];
  const int b = blockIdx.x, t = threadIdx.x;

  const float* pbb = part + (size_t)b * 32768;
  for (int e = t; e < 4 * 2048; e += 256) {
    int h = e >> 11, idx = e & 2047;
    if (idx < 1088) {
      const float* p = pbb + h * 8192 + idx;
      float s = p[0] + p[2048] + p[2 * 2048] + p[3 * 2048];
      if (idx < 1024) La[h][idx >> 5][idx & 31] = s;
      else if (idx < 1056) sq2[h * 32 + (idx - 1024)] = s;
      else sq2[128 + h * 32 + (idx - 1056)] = s;
    }
  }
  __syncthreads();
  rn[t] = 1.f / fmaxf(sqrtf(sq2[t]), 1e-12f);
  __syncthreads();
  for (int e = t; e < 4096; e += 256) {
    int h = e >> 10, i = (e >> 5) & 31, j = e & 31;
    La[h][i][j] *= rn[h * 32 + i] * rn[128 + h * 32 + j] * temperature[h];
  }
  __syncthreads();

  if (t < 128) {
    int h = t >> 5, i = t & 31;
    float m = -1e30f;
    for (int j = 0; j < 32; j++) m = fmaxf(m, La[h][i][j]);
    float S0 = 0.f, S1 = 0.f, S2 = 0.f, S3 = 0.f;
    for (int j = 0; j < 32; j++) {
      float vj = La[h][i][j];
      int r = 0;
      for (int j2 = 0; j2 < 32; j2++) {
        float v2 = La[h][i][j2];
        r += (v2 > vj) || (v2 == vj && j2 < j);
      }
      float e = __expf(vj - m);
      exL[h][i][j] = e;
      rkL[h][i][j] = (unsigned char)r;
      if (r < 16) S0 += e;
      if (r < 21) S1 += e;
      if (r < 24) S2 += e;
      if (r < 25) S3 += e;
    }
    float w0 = attn_w[0] / S0, w1 = attn_w[1] / S1;
    float w2 = attn_w[2] / S2, w3 = attn_w[3] / S3;
    for (int j = 0; j < 32; j++) {
      int r = rkL[h][i][j];
      float cmb = (r < 16 ? w0 : 0.f) + (r < 21 ? w1 : 0.f) +
                  (r < 24 ? w2 : 0.f) + (r < 25 ? w3 : 0.f);
      AwtT[h][j][i] = f2b(exL[h][i][j] * cmb);
    }
  }
  __syncthreads();

  {
    const int wv = t >> 6, l = t & 63, quad = l >> 4, lm = l & 15;
    const int h = wv;
    bf16x8 bfr[2];
#pragma unroll
    for (int jt = 0; jt < 2; jt++)
      bfr[jt] = *(const bf16x8*)&AwtT[h][jt * 16 + lm][quad * 8];
#pragma unroll
    for (int mt = 0; mt < 8; mt++) {
      bf16x8 a = *(const bf16x8*)(proj_wb +
                    (size_t)(mt * 16 + lm) * CD + h * C_ + quad * 8);
#pragma unroll
      for (int jt = 0; jt < 2; jt++) {
        floatx4 acc = (floatx4){0.f, 0.f, 0.f, 0.f};
        acc = MFMA16(a, bfr[jt], acc);
#pragma unroll
        for (int r = 0; r < 4; r++) {
          int row = quad * 4 + r;
          Mb[(size_t)b * 16384 + (mt * 16 + row) * CD + h * C_ + jt * 16 + lm] =
              f2b(acc[r]);
        }
      }
    }
  }
}

// ---------------------------------------------------------------------------
// K6: out[b] = Mb @ V^T + proj_b. Round-0 version: A (Mb) per-ks from global
// (L2-hot, no hoist); LDS = Bs only -> 4 blocks/CU. grid (32, 32), 256 thr.
// ---------------------------------------------------------------------------
__global__ __launch_bounds__(256, 4) void k6_out(
    const unsigned short* __restrict__ vT, const unsigned short* __restrict__ Mb,
    const float* __restrict__ proj_b, float* __restrict__ out)
{
  __shared__ unsigned short Bs[128 * 136];
  const int t = threadIdx.x;
  const int y0 = blockIdx.x * 128, b = blockIdx.y;
  const int wv = t >> 6, l = t & 63, quad = l >> 4, lm = l & 15;

#pragma unroll
  for (int i = 0; i < 8; i++) {
    int f = i * 256 + t;
    int row = f >> 4, c8 = (f & 15) * 8;
    *(uint4*)&Bs[row * 136 + c8] =
        *(const uint4*)(vT + ((size_t)b * N + y0 + row) * CD + c8);
  }
  __syncthreads();

  floatx4 acc[2][8];
#pragma unroll
  for (int mt = 0; mt < 2; mt++)
#pragma unroll
    for (int nt = 0; nt < 8; nt++) acc[mt][nt] = (floatx4){0.f, 0.f, 0.f, 0.f};

  const unsigned short* mbase =
      Mb + (size_t)b * 16384 + (size_t)(wv * 32 + lm) * CD + quad * 8;
#pragma unroll
  for (int ks = 0; ks < 4; ks++) {
    bf16x8 a0 = *(const bf16x8*)(mbase + ks * 32);
    bf16x8 a1 = *(const bf16x8*)(mbase + 16 * CD + ks * 32);
#pragma unroll
    for (int nt = 0; nt < 8; nt++) {
      bf16x8 bb = *(const bf16x8*)&Bs[(nt * 16 + lm) * 136 + ks * 32 + quad * 8];
      acc[0][nt] = MFMA16(a0, bb, acc[0][nt]);
      acc[1][nt] = MFMA16(a1, bb, acc[1][nt]);
    }
  }

#pragma unroll
  for (int mt = 0; mt < 2; mt++)
#pragma unroll
    for (int r = 0; r < 4; r++) {
      int o = wv * 32 + mt * 16 + quad * 4 + r;
      float pb = proj_b[o];
#pragma unroll
      for (int nt = 0; nt < 8; nt++) {
        int y = y0 + nt * 16 + lm;
        out[((size_t)b * CD + o) * N + y] = acc[mt][nt][r] + pb;
      }
    }
}

extern "C" void kernel_launch(void* const* d_in, const int* in_sizes, int n_in,
                              void* d_out, int out_size, void* d_ws, size_t ws_size,
                              hipStream_t stream)
{
  (void)in_sizes; (void)n_in; (void)out_size; (void)ws_size;
  const float* x           = (const float*)d_in[0];
  const float* qkv_w       = (const float*)d_in[1];
  const float* qkv_b       = (const float*)d_in[2];
  const float* dw_w        = (const float*)d_in[3];
  const float* dw_b        = (const float*)d_in[4];
  const float* proj_w      = (const float*)d_in[5];
  const float* proj_b      = (const float*)d_in[6];
  const float* temperature = (const float*)d_in[7];
  const float* attn_w      = (const float*)d_in[8];
  float* out = (float*)d_out;

  unsigned short* xT      = (unsigned short*)d_ws;   // 16,777,216 sh
  unsigned short* qkv_wb  = xT + (size_t)16777216;   //     49,152
  unsigned short* proj_wb = qkv_wb + 49152;          //     16,384
  unsigned short* qkvd    = proj_wb + 16384;         // 33,554,432 (q,k)
  unsigned short* vT      = qkvd + (size_t)33554432; // 16,777,216
  unsigned short* Mb      = vT + (size_t)16777216;   //    524,288
  float* part = (float*)(Mb + 524288);               //  1,048,576 f
  // dwq (384 float4 = 6 KiB) aliases Mb: written by k0_w, read by k1,
  // dead before k45 writes Mb. 16B-aligned (Mb offset is 16B-multiple).
  float4* dwq = (float4*)Mb;

  k0_xt    <<<dim3(64, 4, 32),  256, 0, stream>>>(x, xT);
  k0_w     <<<dim3(66),         256, 0, stream>>>(qkv_w, proj_w, dw_w, dw_b,
                                                  qkv_wb, proj_wb, dwq);
  k1_qkv_dw<<<dim3(3, 34, 32),  256, 0, stream>>>(xT, qkv_wb, qkv_b, dwq,
                                                  qkvd, vT);
  k3_gram  <<<dim3(4, H_, B_),  256, 0, stream>>>(qkvd, part);
  k45      <<<dim3(B_),         256, 0, stream>>>(part, proj_wb, temperature,
                                                  attn_w, Mb);
  k6_out   <<<dim3(32, B_),     256, 0, stream>>>(vT, Mb, proj_b, out);
}